// Round 21
// baseline (57.857 us; speedup 1.0000x reference)
//
#include <hip/hip_runtime.h>
#include <math.h>

#define BB 8
#define TT 256
#define UU 128      // U
#define U1 129      // U+1
#define VV 256
#define ND 384      // anti-diagonals d = t+u
#define WROW 264    // floats per diag row: {pb[u],pl[u]} pairs u=0..128 + pad
#define PF 16       // diagonals per ring slot (R19's proven config)
#define NLN2_9  6.238324625f    // 9*ln2 (per-step spurious gain from the *512)
#define NLN2_29 20.10126823f    // 29*ln2 (rescale offset: anchor -> 2^-29)
#define TWO_M29 1.862645149e-9f // 2^-29

// wave-wide shift-right-by-1 via DPP; lane0 reads 0 (= additive identity
// in linear space: the u=0 boundary guard is free)
__device__ __forceinline__ float wave_shr1(float x) {
    int r = __builtin_amdgcn_update_dpp(0, __float_as_int(x), 0x138, 0xf, 0xf, true);
    return __int_as_float(r);
}

template <int CTRL>
__device__ __forceinline__ float dppadd(float x) {
    int t = __builtin_amdgcn_update_dpp(0, __float_as_int(x), CTRL, 0xf, 0xf, true);
    return x + __int_as_float(t);
}

// full-wave sum via 6 DPP VALU adds; result broadcast from lane 63
__device__ __forceinline__ float wave_sum(float s) {
    s = dppadd<0x111>(s); s = dppadd<0x112>(s); s = dppadd<0x114>(s);
    s = dppadd<0x118>(s); s = dppadd<0x142>(s); s = dppadd<0x143>(s);
    return __int_as_float(__builtin_amdgcn_readlane(__float_as_int(s), 63));
}

__device__ __forceinline__ float readlane_f(float x, int l) {
    return __int_as_float(__builtin_amdgcn_readlane(__float_as_int(x), l));
}

typedef float f4 __attribute__((ext_vector_type(4)));

// Kernel 1: 4 rows/wave, dead-skip, no-max LSE, DPP reduce, parallel float2
// epilogue; stores LINEAR-space scaled probabilities pb=exp(blk)*512,
// pl=exp(lbl)*512 (512=2^9 ~ cancels the e^-6.2 mean per-step decay).
__global__ __launch_bounds__(256) void k_logprobs(
    const float* __restrict__ acts, const int* __restrict__ labels,
    const int* __restrict__ act_lens, const int* __restrict__ label_lens,
    float* __restrict__ wsD, float* __restrict__ bD128)
{
    const int NQUAD = BB * TT * U1 / 4;                 // 66048
    int qid = (blockIdx.x << 2) + (threadIdx.x >> 6);
    if (qid >= NQUAD) return;
    qid = __builtin_amdgcn_readfirstlane(qid);
    int lane = threadIdx.x & 63;
    int wid0 = qid * 4;

    int b = wid0 / (TT * U1);                           // uniform (33024 % 4 == 0)
    int flen = act_lens[b];
    int glen = label_lens[b];

    int tt[4], uu[4]; bool keep[4]; f4 v[4];
    #pragma unroll
    for (int r = 0; r < 4; ++r) {
        int wid = wid0 + r;
        int rem = wid - b * (TT * U1);
        int t = rem / U1;
        int u = rem - t * U1;
        tt[r] = t; uu[r] = u;
        keep[r] = (t < flen) && (u <= glen);
        v[r] = (f4){0.f, 0.f, 0.f, 0.f};
        if (keep[r])
            v[r] = __builtin_nontemporal_load((const f4*)(acts + (size_t)wid * VV) + lane);
    }

    float labv[4];
    #pragma unroll
    for (int r = 0; r < 4; ++r) {
        labv[r] = 0.f;
        if (keep[r] && uu[r] < UU)
            labv[r] = acts[(size_t)(wid0 + r) * VV + labels[b * UU + uu[r]]];
    }

    float lse[4];
    #pragma unroll
    for (int r = 0; r < 4; ++r) {
        float s = __expf(v[r].x) + __expf(v[r].y) + __expf(v[r].z) + __expf(v[r].w);
        lse[r] = __logf(wave_sum(s));
    }

    float mypb = 0.f, mypl = 0.f; int myd = 0, myu = 0; bool mykeep = false;
    #pragma unroll
    for (int r = 0; r < 4; ++r) {
        float bs = readlane_f(v[r].x, 0);               // BLANK logit
        if (lane == r) {
            mypb = __expf(bs - lse[r]) * 512.f;
            mypl = __expf(labv[r] - lse[r]) * 512.f;    // u==128: garbage, pad, unread
            myd = tt[r] + uu[r]; myu = uu[r]; mykeep = keep[r];
        }
    }
    if (lane < 4 && mykeep) {
        float2 val = make_float2(mypb, mypl);
        *(float2*)(wsD + (size_t)(b * ND + myd) * WROW + 2 * myu) = val;
        if (myu == UU) bD128[b * ND + myd] = mypb;
    }
}

// Kernel 2: R19's verified linear-space FMA DP (PF=16, 4-slot ring) with
// ONE change: final -ll is atomicAdd'ed into out[0] (k_sum launch + gap
// eliminated; out zeroed by hipMemsetAsync each call).
__global__ __launch_bounds__(256, 1) void k_dp(
    const float* __restrict__ wsD, const float* __restrict__ bD128,
    const int* __restrict__ act_lens, const int* __restrict__ label_lens,
    float* __restrict__ out)
{
    __shared__ __align__(16) float ring[4][PF * 256];   // 4 x 16KB
    __shared__ __align__(16) float ldsF[ND + 32];       // pb[128] per diag

    int b = blockIdx.x;
    int tid = threadIdx.x;
    int wave = tid >> 6;
    int lane = tid & 63;
    const float* Wd = wsD + (size_t)b * ND * WROW;
    const float* Bg = bD128 + b * ND;
    int flen = act_lens[b];
    int glen = label_lens[b];
    int dstar = flen - 1 + glen;        // in [191, 383]
    int pmax  = (dstar - 1) / PF;
    float invds = 1.0f / (float)dstar;

    const int u0 = 2 * lane;
    const bool lane0  = (lane == 0);
    const bool isg0   = (u0 == glen);
    const bool isg1   = (u0 + 1 == glen);
    const bool isg128 = (lane == 63) && (glen == 128);
    const bool have   = isg0 | isg1 | isg128;

    if (wave == 0) {
        #pragma unroll
        for (int k = 0; k < 6; ++k)
            ldsF[k * 64 + lane] = Bg[k * 64 + lane];
    } else {
        // prologue: batch-fill slots 0,1 with diags 0..31 (named regs)
        const int base = (wave - 1) * 11;
        #define PROW(k) ((base + (k) > 31) ? 31 : base + (k))
        f4 pv0, pv1, pv2, pv3, pv4, pv5, pv6, pv7, pv8, pv9, pv10;
        pv0  = *(const f4*)(Wd + (size_t)PROW(0)  * WROW + 4 * lane);
        pv1  = *(const f4*)(Wd + (size_t)PROW(1)  * WROW + 4 * lane);
        pv2  = *(const f4*)(Wd + (size_t)PROW(2)  * WROW + 4 * lane);
        pv3  = *(const f4*)(Wd + (size_t)PROW(3)  * WROW + 4 * lane);
        pv4  = *(const f4*)(Wd + (size_t)PROW(4)  * WROW + 4 * lane);
        pv5  = *(const f4*)(Wd + (size_t)PROW(5)  * WROW + 4 * lane);
        pv6  = *(const f4*)(Wd + (size_t)PROW(6)  * WROW + 4 * lane);
        pv7  = *(const f4*)(Wd + (size_t)PROW(7)  * WROW + 4 * lane);
        pv8  = *(const f4*)(Wd + (size_t)PROW(8)  * WROW + 4 * lane);
        pv9  = *(const f4*)(Wd + (size_t)PROW(9)  * WROW + 4 * lane);
        pv10 = *(const f4*)(Wd + (size_t)PROW(10) * WROW + 4 * lane);
        __builtin_amdgcn_sched_barrier(0);
        #define PWRITE(k, v) *(f4*)&ring[PROW(k) >> 4][(PROW(k) & 15) * 256 + 4 * lane] = v
        PWRITE(0, pv0);  PWRITE(1, pv1);  PWRITE(2, pv2);  PWRITE(3, pv3);
        PWRITE(4, pv4);  PWRITE(5, pv5);  PWRITE(6, pv6);  PWRITE(7, pv7);
        PWRITE(8, pv8);  PWRITE(9, pv9);  PWRITE(10, pv10);
        #undef PWRITE
        #undef PROW
    }
    __syncthreads();

    float a0 = lane0 ? 1.0f : 0.0f;     // A(u=2*lane), linear space
    float a1 = 0.0f;                    // A(u=2*lane+1)
    float a2 = 0.0f;                    // A(u=128), lane 63 only meaningful
    float ls = 0.0f;                    // rescale adjustments accumulator
    float saved = 0.0f;

    #pragma unroll 1
    for (int p = 0; p <= pmax; ++p) {
        int dbase = 1 + p * PF;
        if (wave == 0) {
            // band-centered rescale once per phase (anchor provably live;
            // anchor == target cell at d=dstar so 'saved' is well-scaled)
            if (p > 0) {
                int uc = (int)((float)(glen * (dbase - 1)) * invds);
                float s = readlane_f(a0, uc >> 1);
                float f = TWO_M29 / s;
                a0 *= f; a1 *= f; a2 *= f;
                ls += __logf(s) + NLN2_29;
            }
            const float* slot = ring[p & 3];
            float b128v = (lane < PF) ? ldsF[dbase - 1 + lane] : 0.f;
            f4 wreg[PF]; float plm[PF];
            #pragma unroll
            for (int j = 0; j < PF; ++j)
                wreg[j] = *(const f4*)(slot + j * 256 + 4 * lane);
            #pragma unroll
            for (int j = 0; j < PF; ++j)
                plm[j] = wave_shr1(wreg[j].w);          // pl[u0-1], off-chain
            #pragma unroll
            for (int j = 0; j < PF; ++j) {
                int d = dbase + j;
                float bj = readlane_f(b128v, j);
                float pm = wave_shr1(a1);               // A[u0-1] (0 at lane0)
                float n0 = fmaf(a0, wreg[j].x, pm * plm[j]);
                float n1 = fmaf(a1, wreg[j].z, a0 * wreg[j].y);
                float n2 = fmaf(a2, bj,        a1 * wreg[j].w);
                if (d == dstar) {                       // uniform, true once
                    float s1 = isg1 ? n1 : (isg128 ? n2 : 0.0f);
                    saved = isg0 ? n0 : s1;
                }
                a0 = n0; a1 = n1; a2 = n2;
            }
        } else {
            // producers: batch-fill slot (p+2)%4 (diags fbase-1+j), named regs
            int fbase = dbase + 2 * PF;
            if (fbase <= dstar) {
                float* slot = ring[(p + 2) & 3];
                const int base = (wave - 1) * 6;
                #define SROW(k) ((base + (k) > 15) ? 15 : base + (k))
                #define SDIAG(k) (((fbase - 1 + SROW(k)) > ND - 1) ? ND - 1 : fbase - 1 + SROW(k))
                f4 pv0, pv1, pv2, pv3, pv4, pv5;
                pv0 = *(const f4*)(Wd + (size_t)SDIAG(0) * WROW + 4 * lane);
                pv1 = *(const f4*)(Wd + (size_t)SDIAG(1) * WROW + 4 * lane);
                pv2 = *(const f4*)(Wd + (size_t)SDIAG(2) * WROW + 4 * lane);
                pv3 = *(const f4*)(Wd + (size_t)SDIAG(3) * WROW + 4 * lane);
                pv4 = *(const f4*)(Wd + (size_t)SDIAG(4) * WROW + 4 * lane);
                pv5 = *(const f4*)(Wd + (size_t)SDIAG(5) * WROW + 4 * lane);
                __builtin_amdgcn_sched_barrier(0);
                *(f4*)&slot[SROW(0) * 256 + 4 * lane] = pv0;
                *(f4*)&slot[SROW(1) * 256 + 4 * lane] = pv1;
                *(f4*)&slot[SROW(2) * 256 + 4 * lane] = pv2;
                *(f4*)&slot[SROW(3) * 256 + 4 * lane] = pv3;
                *(f4*)&slot[SROW(4) * 256 + 4 * lane] = pv4;
                *(f4*)&slot[SROW(5) * 256 + 4 * lane] = pv5;
                #undef SROW
                #undef SDIAG
            }
        }
        __syncthreads();
    }

    if (wave == 0 && have) {
        // true ll = log(saved) + ls - 9ln2*dstar + log(pb_fin/512)
        float pbF = Wd[(size_t)dstar * WROW + 2 * glen];   // 512*p_blank(final)
        float ll = __logf(saved) + ls - NLN2_9 * (float)dstar + __logf(pbF) - NLN2_9;
        atomicAdd(out, -ll);            // device-scope; out zeroed per call
    }
}

extern "C" void kernel_launch(void* const* d_in, const int* in_sizes, int n_in,
                              void* d_out, int out_size, void* d_ws, size_t ws_size,
                              hipStream_t stream) {
    const float* acts      = (const float*)d_in[0];
    const int*   labels    = (const int*)d_in[1];
    const int*   act_lens  = (const int*)d_in[2];
    const int*   label_lens= (const int*)d_in[3];
    float* out = (float*)d_out;

    float* wsD   = (float*)d_ws;                       // 8*384*264 floats = 3.24 MB
    float* bD128 = wsD + (size_t)BB * ND * WROW;       // 8*384 floats

    hipMemsetAsync(out, 0, sizeof(float), stream);     // graph-legal async memset

    const int NQUAD = BB * TT * U1 / 4;                // 66048 waves
    int blocks = NQUAD / 4;                            // 16512 (exact)

    k_logprobs<<<blocks, 256, 0, stream>>>(acts, labels, act_lens, label_lens, wsD, bD128);
    k_dp<<<BB, 256, 0, stream>>>(wsD, bD128, act_lens, label_lens, out);
}

// Round 22
// 53.543 us; speedup vs baseline: 1.0806x; 1.0806x over previous
//
#include <hip/hip_runtime.h>
#include <math.h>

#define BB 8
#define TT 256
#define UU 128      // U
#define U1 129      // U+1
#define VV 256
#define ND 384      // anti-diagonals d = t+u
#define WROW 264    // floats per diag row: {pb[u],pl[u]} pairs u=0..128 + pad
#define PF 16       // diagonals per ring slot (R19's proven config)
#define NLN2_9  6.238324625f    // 9*ln2 (per-step spurious gain from the *512)
#define NLN2_29 20.10126823f    // 29*ln2 (rescale offset: anchor -> 2^-29)
#define TWO_M29 1.862645149e-9f // 2^-29

// wave-wide shift-right-by-1 via DPP; lane0 reads 0 (= additive identity
// in linear space: the u=0 boundary guard is free)
__device__ __forceinline__ float wave_shr1(float x) {
    int r = __builtin_amdgcn_update_dpp(0, __float_as_int(x), 0x138, 0xf, 0xf, true);
    return __int_as_float(r);
}

template <int CTRL>
__device__ __forceinline__ float dppadd(float x) {
    int t = __builtin_amdgcn_update_dpp(0, __float_as_int(x), CTRL, 0xf, 0xf, true);
    return x + __int_as_float(t);
}

// full-wave sum via 6 DPP VALU adds; result broadcast from lane 63
__device__ __forceinline__ float wave_sum(float s) {
    s = dppadd<0x111>(s); s = dppadd<0x112>(s); s = dppadd<0x114>(s);
    s = dppadd<0x118>(s); s = dppadd<0x142>(s); s = dppadd<0x143>(s);
    return __int_as_float(__builtin_amdgcn_readlane(__float_as_int(s), 63));
}

__device__ __forceinline__ float readlane_f(float x, int l) {
    return __int_as_float(__builtin_amdgcn_readlane(__float_as_int(x), l));
}

typedef float f4 __attribute__((ext_vector_type(4)));

// Kernel 1: 4 rows/wave, dead-skip, no-max LSE, DPP reduce, parallel float2
// epilogue; stores LINEAR-space scaled probabilities pb=exp(blk)*512,
// pl=exp(lbl)*512 (512=2^9 ~ cancels the e^-6.2 mean per-step decay).
__global__ __launch_bounds__(256) void k_logprobs(
    const float* __restrict__ acts, const int* __restrict__ labels,
    const int* __restrict__ act_lens, const int* __restrict__ label_lens,
    float* __restrict__ wsD, float* __restrict__ bD128)
{
    const int NQUAD = BB * TT * U1 / 4;                 // 66048
    int qid = (blockIdx.x << 2) + (threadIdx.x >> 6);
    if (qid >= NQUAD) return;
    qid = __builtin_amdgcn_readfirstlane(qid);
    int lane = threadIdx.x & 63;
    int wid0 = qid * 4;

    int b = wid0 / (TT * U1);                           // uniform (33024 % 4 == 0)
    int flen = act_lens[b];
    int glen = label_lens[b];

    int tt[4], uu[4]; bool keep[4]; f4 v[4];
    #pragma unroll
    for (int r = 0; r < 4; ++r) {
        int wid = wid0 + r;
        int rem = wid - b * (TT * U1);
        int t = rem / U1;
        int u = rem - t * U1;
        tt[r] = t; uu[r] = u;
        keep[r] = (t < flen) && (u <= glen);
        v[r] = (f4){0.f, 0.f, 0.f, 0.f};
        if (keep[r])
            v[r] = __builtin_nontemporal_load((const f4*)(acts + (size_t)wid * VV) + lane);
    }

    float labv[4];
    #pragma unroll
    for (int r = 0; r < 4; ++r) {
        labv[r] = 0.f;
        if (keep[r] && uu[r] < UU)
            labv[r] = acts[(size_t)(wid0 + r) * VV + labels[b * UU + uu[r]]];
    }

    float lse[4];
    #pragma unroll
    for (int r = 0; r < 4; ++r) {
        float s = __expf(v[r].x) + __expf(v[r].y) + __expf(v[r].z) + __expf(v[r].w);
        lse[r] = __logf(wave_sum(s));
    }

    float mypb = 0.f, mypl = 0.f; int myd = 0, myu = 0; bool mykeep = false;
    #pragma unroll
    for (int r = 0; r < 4; ++r) {
        float bs = readlane_f(v[r].x, 0);               // BLANK logit
        if (lane == r) {
            mypb = __expf(bs - lse[r]) * 512.f;
            mypl = __expf(labv[r] - lse[r]) * 512.f;    // u==128: garbage, pad, unread
            myd = tt[r] + uu[r]; myu = uu[r]; mykeep = keep[r];
        }
    }
    if (lane < 4 && mykeep) {
        float2 val = make_float2(mypb, mypl);
        *(float2*)(wsD + (size_t)(b * ND + myd) * WROW + 2 * myu) = val;
        if (myu == UU) bD128[b * ND + myd] = mypb;
    }
}

// Kernel 2: R19's verified linear-space FMA DP (PF=16, 4-slot ring, separate
// k_sum — the measured-best 54.6us config), with ONE micro-change: n0 is
// reassociated fma(pm, plm, a0*wx) so a0*wx issues in parallel with the DPP
// (chain: DPP->fma = 2 dep ops instead of DPP->mul->fma = 3).
__global__ __launch_bounds__(256, 1) void k_dp(
    const float* __restrict__ wsD, const float* __restrict__ bD128,
    const int* __restrict__ act_lens, const int* __restrict__ label_lens,
    float* __restrict__ costs)
{
    __shared__ __align__(16) float ring[4][PF * 256];   // 4 x 16KB
    __shared__ __align__(16) float ldsF[ND + 32];       // pb[128] per diag

    int b = blockIdx.x;
    int tid = threadIdx.x;
    int wave = tid >> 6;
    int lane = tid & 63;
    const float* Wd = wsD + (size_t)b * ND * WROW;
    const float* Bg = bD128 + b * ND;
    int flen = act_lens[b];
    int glen = label_lens[b];
    int dstar = flen - 1 + glen;        // in [191, 383]
    int pmax  = (dstar - 1) / PF;
    float invds = 1.0f / (float)dstar;

    const int u0 = 2 * lane;
    const bool lane0  = (lane == 0);
    const bool isg0   = (u0 == glen);
    const bool isg1   = (u0 + 1 == glen);
    const bool isg128 = (lane == 63) && (glen == 128);
    const bool have   = isg0 | isg1 | isg128;

    if (wave == 0) {
        #pragma unroll
        for (int k = 0; k < 6; ++k)
            ldsF[k * 64 + lane] = Bg[k * 64 + lane];
    } else {
        // prologue: batch-fill slots 0,1 with diags 0..31 (named regs)
        const int base = (wave - 1) * 11;
        #define PROW(k) ((base + (k) > 31) ? 31 : base + (k))
        f4 pv0, pv1, pv2, pv3, pv4, pv5, pv6, pv7, pv8, pv9, pv10;
        pv0  = *(const f4*)(Wd + (size_t)PROW(0)  * WROW + 4 * lane);
        pv1  = *(const f4*)(Wd + (size_t)PROW(1)  * WROW + 4 * lane);
        pv2  = *(const f4*)(Wd + (size_t)PROW(2)  * WROW + 4 * lane);
        pv3  = *(const f4*)(Wd + (size_t)PROW(3)  * WROW + 4 * lane);
        pv4  = *(const f4*)(Wd + (size_t)PROW(4)  * WROW + 4 * lane);
        pv5  = *(const f4*)(Wd + (size_t)PROW(5)  * WROW + 4 * lane);
        pv6  = *(const f4*)(Wd + (size_t)PROW(6)  * WROW + 4 * lane);
        pv7  = *(const f4*)(Wd + (size_t)PROW(7)  * WROW + 4 * lane);
        pv8  = *(const f4*)(Wd + (size_t)PROW(8)  * WROW + 4 * lane);
        pv9  = *(const f4*)(Wd + (size_t)PROW(9)  * WROW + 4 * lane);
        pv10 = *(const f4*)(Wd + (size_t)PROW(10) * WROW + 4 * lane);
        __builtin_amdgcn_sched_barrier(0);
        #define PWRITE(k, v) *(f4*)&ring[PROW(k) >> 4][(PROW(k) & 15) * 256 + 4 * lane] = v
        PWRITE(0, pv0);  PWRITE(1, pv1);  PWRITE(2, pv2);  PWRITE(3, pv3);
        PWRITE(4, pv4);  PWRITE(5, pv5);  PWRITE(6, pv6);  PWRITE(7, pv7);
        PWRITE(8, pv8);  PWRITE(9, pv9);  PWRITE(10, pv10);
        #undef PWRITE
        #undef PROW
    }
    __syncthreads();

    float a0 = lane0 ? 1.0f : 0.0f;     // A(u=2*lane), linear space
    float a1 = 0.0f;                    // A(u=2*lane+1)
    float a2 = 0.0f;                    // A(u=128), lane 63 only meaningful
    float ls = 0.0f;                    // rescale adjustments accumulator
    float saved = 0.0f;

    #pragma unroll 1
    for (int p = 0; p <= pmax; ++p) {
        int dbase = 1 + p * PF;
        if (wave == 0) {
            // band-centered rescale once per phase (anchor provably live;
            // anchor == target cell at d=dstar so 'saved' is well-scaled)
            if (p > 0) {
                int uc = (int)((float)(glen * (dbase - 1)) * invds);
                float s = readlane_f(a0, uc >> 1);
                float f = TWO_M29 / s;
                a0 *= f; a1 *= f; a2 *= f;
                ls += __logf(s) + NLN2_29;
            }
            const float* slot = ring[p & 3];
            float b128v = (lane < PF) ? ldsF[dbase - 1 + lane] : 0.f;
            f4 wreg[PF]; float plm[PF];
            #pragma unroll
            for (int j = 0; j < PF; ++j)
                wreg[j] = *(const f4*)(slot + j * 256 + 4 * lane);
            #pragma unroll
            for (int j = 0; j < PF; ++j)
                plm[j] = wave_shr1(wreg[j].w);          // pl[u0-1], off-chain
            #pragma unroll
            for (int j = 0; j < PF; ++j) {
                int d = dbase + j;
                float bj = readlane_f(b128v, j);
                float pm = wave_shr1(a1);               // A[u0-1] (0 at lane0)
                // a0*wx issues in parallel with the DPP: chain = DPP -> fma
                float n0 = fmaf(pm, plm[j], a0 * wreg[j].x);
                float n1 = fmaf(a1, wreg[j].z, a0 * wreg[j].y);
                float n2 = fmaf(a2, bj,        a1 * wreg[j].w);
                if (d == dstar) {                       // uniform, true once
                    float s1 = isg1 ? n1 : (isg128 ? n2 : 0.0f);
                    saved = isg0 ? n0 : s1;
                }
                a0 = n0; a1 = n1; a2 = n2;
            }
        } else {
            // producers: batch-fill slot (p+2)%4 (diags fbase-1+j), named regs
            int fbase = dbase + 2 * PF;
            if (fbase <= dstar) {
                float* slot = ring[(p + 2) & 3];
                const int base = (wave - 1) * 6;
                #define SROW(k) ((base + (k) > 15) ? 15 : base + (k))
                #define SDIAG(k) (((fbase - 1 + SROW(k)) > ND - 1) ? ND - 1 : fbase - 1 + SROW(k))
                f4 pv0, pv1, pv2, pv3, pv4, pv5;
                pv0 = *(const f4*)(Wd + (size_t)SDIAG(0) * WROW + 4 * lane);
                pv1 = *(const f4*)(Wd + (size_t)SDIAG(1) * WROW + 4 * lane);
                pv2 = *(const f4*)(Wd + (size_t)SDIAG(2) * WROW + 4 * lane);
                pv3 = *(const f4*)(Wd + (size_t)SDIAG(3) * WROW + 4 * lane);
                pv4 = *(const f4*)(Wd + (size_t)SDIAG(4) * WROW + 4 * lane);
                pv5 = *(const f4*)(Wd + (size_t)SDIAG(5) * WROW + 4 * lane);
                __builtin_amdgcn_sched_barrier(0);
                *(f4*)&slot[SROW(0) * 256 + 4 * lane] = pv0;
                *(f4*)&slot[SROW(1) * 256 + 4 * lane] = pv1;
                *(f4*)&slot[SROW(2) * 256 + 4 * lane] = pv2;
                *(f4*)&slot[SROW(3) * 256 + 4 * lane] = pv3;
                *(f4*)&slot[SROW(4) * 256 + 4 * lane] = pv4;
                *(f4*)&slot[SROW(5) * 256 + 4 * lane] = pv5;
                #undef SROW
                #undef SDIAG
            }
        }
        __syncthreads();
    }

    if (wave == 0 && have) {
        // true ll = log(saved) + ls - 9ln2*dstar + log(pb_fin/512)
        float pbF = Wd[(size_t)dstar * WROW + 2 * glen];   // 512*p_blank(final)
        float ll = __logf(saved) + ls - NLN2_9 * (float)dstar + __logf(pbF) - NLN2_9;
        costs[b] = -ll;
    }
}

__global__ void k_sum(const float* __restrict__ costs, float* __restrict__ out)
{
    if (threadIdx.x == 0 && blockIdx.x == 0) {
        float s = 0.0f;
        for (int i = 0; i < BB; ++i) s += costs[i];
        out[0] = s;
    }
}

extern "C" void kernel_launch(void* const* d_in, const int* in_sizes, int n_in,
                              void* d_out, int out_size, void* d_ws, size_t ws_size,
                              hipStream_t stream) {
    const float* acts      = (const float*)d_in[0];
    const int*   labels    = (const int*)d_in[1];
    const int*   act_lens  = (const int*)d_in[2];
    const int*   label_lens= (const int*)d_in[3];
    float* out = (float*)d_out;

    float* wsD   = (float*)d_ws;                       // 8*384*264 floats = 3.24 MB
    float* bD128 = wsD + (size_t)BB * ND * WROW;       // 8*384 floats
    float* costs = (float*)d_ws + (8u << 20);          // 32 MB in

    const int NQUAD = BB * TT * U1 / 4;                // 66048 waves
    int blocks = NQUAD / 4;                            // 16512 (exact)

    k_logprobs<<<blocks, 256, 0, stream>>>(acts, labels, act_lens, label_lens, wsD, bD128);
    k_dp<<<BB, 256, 0, stream>>>(wsD, bD128, act_lens, label_lens, costs);
    k_sum<<<1, 64, 0, stream>>>(costs, out);
}